// Round 14
// baseline (352.056 us; speedup 1.0000x reference)
//
#include <hip/hip_runtime.h>
#include <hip/hip_bf16.h>

typedef __attribute__((ext_vector_type(4))) float f32x4;
typedef __attribute__((ext_vector_type(8))) short short8;
typedef __attribute__((ext_vector_type(4))) unsigned short us4;
typedef __attribute__((ext_vector_type(2))) unsigned short us2;
typedef unsigned short u16;

__device__ __forceinline__ float bf2f(u16 u) {
  unsigned int x = ((unsigned int)u) << 16;
  float f; __builtin_memcpy(&f, &x, 4); return f;
}
__device__ __forceinline__ u16 f2bf(float f) {
  __hip_bfloat16 h = __float2bfloat16(f);
  u16 u; __builtin_memcpy(&u, &h, 2); return u;
}

// async global->LDS, 16B per lane. LDS dest must be (wave-uniform base + lane*16).
#define GLL16(g, l) __builtin_amdgcn_global_load_lds( \
    (const __attribute__((address_space(1))) unsigned int*)(g), \
    (__attribute__((address_space(3))) unsigned int*)(l), 16, 0, 0)

#define MFMA16x32(a, b, c) __builtin_amdgcn_mfma_f32_16x16x32_bf16(a, b, c, 0, 0, 0)

// ---------------- conversion kernels ----------------

__global__ __launch_bounds__(256) void k_convert_x(const float* __restrict__ x1,
                                                   const float* __restrict__ x2,
                                                   u16* __restrict__ xc) {
  int tid = blockIdx.x * 256 + threadIdx.x;
  int e = tid * 8;
  int m = e >> 11, d = e & 2047;
  int b = m >> 11, n = m & 2047;
  const float* src = (n < 1024) ? (x1 + ((b << 10) + n) * 2048 + d)
                                : (x2 + ((b << 10) + n - 1024) * 2048 + d);
  float4 v0 = *(const float4*)src;
  float4 v1 = *(const float4*)(src + 4);
  us4 a = {f2bf(v0.x), f2bf(v0.y), f2bf(v0.z), f2bf(v0.w)};
  us4 c = {f2bf(v1.x), f2bf(v1.y), f2bf(v1.z), f2bf(v1.w)};
  *(us4*)(xc + e) = a;
  *(us4*)(xc + e + 4) = c;
}

struct W8 { const float* w[8]; };

// W f32 [K=2048][N=2048] -> Wt bf16 [N][K]
__global__ __launch_bounds__(256) void k_wt(W8 p, u16* __restrict__ wtbase) {
  __shared__ u16 lt[64][72];
  const float* W = p.w[blockIdx.z];
  u16* Wt = wtbase + (size_t)blockIdx.z * 4194304u;
  int k0 = blockIdx.x * 64, n0 = blockIdx.y * 64;
  int t = threadIdx.x;
#pragma unroll
  for (int i = 0; i < 4; ++i) {
    int lin = t + i * 256;
    int r = lin >> 4, c4 = (lin & 15) * 4;
    float4 v = *(const float4*)&W[(k0 + r) * 2048 + n0 + c4];
    us4 u = {f2bf(v.x), f2bf(v.y), f2bf(v.z), f2bf(v.w)};
    *(us4*)&lt[r][c4] = u;
  }
  __syncthreads();
#pragma unroll
  for (int i = 0; i < 8; ++i) {
    int lin = t + i * 256;
    int rd = lin >> 5, cs = (lin & 31) * 2;
    us2 u = {lt[cs][rd], lt[cs + 1][rd]};
    *(us2*)&Wt[(n0 + rd) * 2048 + k0 + cs] = u;
  }
}

// rope tables [1024][128] f32 -> transposed [128][2048] f32 (cols base..base+1023)
__global__ __launch_bounds__(256) void k_tab(const float* __restrict__ c1,
                                             const float* __restrict__ s1,
                                             const float* __restrict__ c2,
                                             const float* __restrict__ s2,
                                             float* __restrict__ tc,
                                             float* __restrict__ ts) {
  __shared__ float lt[64][65];
  const int z = blockIdx.z;                  // 0:c1 1:c2 2:s1 3:s2
  const float* src = (z == 0) ? c1 : (z == 1) ? c2 : (z == 2) ? s1 : s2;
  float* dst = (z < 2) ? tc : ts;
  const int nbase = (z & 1) * 1024;
  const int r0 = blockIdx.x * 64;            // n rows (0..1023)
  const int c0 = blockIdx.y * 64;            // dh cols (0..127)
  const int t = threadIdx.x;
#pragma unroll
  for (int i = 0; i < 4; ++i) {
    int lin = t + i * 256;
    int r = lin >> 4, c4 = (lin & 15) * 4;
    float4 v = *(const float4*)&src[(r0 + r) * 128 + c0 + c4];
    lt[r][c4] = v.x; lt[r][c4 + 1] = v.y; lt[r][c4 + 2] = v.z; lt[r][c4 + 3] = v.w;
  }
  __syncthreads();
#pragma unroll
  for (int i = 0; i < 4; ++i) {
    int lin = t + i * 256;
    int rd = lin >> 4, cs = (lin & 15) * 4;
    float4 w = {lt[cs][rd], lt[cs + 1][rd], lt[cs + 2][rd], lt[cs + 3][rd]};
    *(float4*)&dst[(c0 + rd) * 2048 + nbase + r0 + cs] = w;
  }
}

// ---------------- 8-phase GEMM core (SB-pinning removed; only rule-#18 SB kept) ----------------
#define BAR() __builtin_amdgcn_s_barrier()
#define VM4() asm volatile("s_waitcnt vmcnt(4)" ::: "memory")
#define LGK0() do { asm volatile("s_waitcnt lgkmcnt(0)" ::: "memory"); \
                    __builtin_amdgcn_sched_barrier(0); } while (0)

__device__ __forceinline__ void gemm256_core(const u16* __restrict__ A,
                                             const u16* __restrict__ Bt,
                                             int m0, int nb,
                                             u16* lA, u16* lB,
                                             f32x4 acc[8][4]) {
  const int t = threadIdx.x;
  const int lane = t & 63, wid = t >> 6;
  const int lq = lane & 15, lg = lane >> 4;
  const int wr = wid >> 2, wc = wid & 3;
  const int swz = (lq & 7) << 4;

  u16* lA0 = lA;  u16* lA1 = lA + 256 * 64;
  u16* lB0 = lB;  u16* lB1 = lB + 256 * 64;

  short8 af[4][2];
  short8 bf[2][2][2];

  auto stage = [&](const u16* G, int grow0, u16* lbase, int h, int kt) {
    const int k0 = (kt & 31) * 64;
#pragma unroll
    for (int j = 0; j < 2; ++j) {
      int c = j * 512 + t;
      int row = c >> 3;
      int colb = (c & 7) * 16;
      int sc = colb ^ ((row & 7) << 4);
      GLL16(G + (size_t)(grow0 + h * 128 + row) * 2048 + k0 + (sc >> 1),
            (u16*)((char*)lbase + (h * 128 + row) * 128 + colb));
    }
  };
  auto rdA = [&](const u16* lbase, int mh) {
#pragma unroll
    for (int mf = 0; mf < 4; ++mf)
#pragma unroll
      for (int kc = 0; kc < 2; ++kc) {
        int row = wr * 128 + (mh * 4 + mf) * 16 + lq;
        af[mf][kc] = *(const short8*)((const char*)lbase + row * 128 +
                                      ((kc * 64 + lg * 16) ^ swz));
      }
  };
  auto rdB = [&](const u16* lbase, int nh) {
#pragma unroll
    for (int nf = 0; nf < 2; ++nf)
#pragma unroll
      for (int kc = 0; kc < 2; ++kc) {
        int row = wc * 64 + (nh * 2 + nf) * 16 + lq;
        bf[nh][nf][kc] = *(const short8*)((const char*)lbase + row * 128 +
                                          ((kc * 64 + lg * 16) ^ swz));
      }
  };
  auto mm = [&](int mh, int nh) {
    __builtin_amdgcn_s_setprio(1);
#pragma unroll
    for (int mf = 0; mf < 4; ++mf)
#pragma unroll
      for (int nf = 0; nf < 2; ++nf)
#pragma unroll
        for (int kc = 0; kc < 2; ++kc)
          acc[mh * 4 + mf][nh * 2 + nf] =
              MFMA16x32(af[mf][kc], bf[nh][nf][kc], acc[mh * 4 + mf][nh * 2 + nf]);
    __builtin_amdgcn_s_setprio(0);
  };

  // prologue: tile0 complete, tile1 {B-h0, A-h0}
  stage(Bt, nb, lB0, 0, 0); stage(A, m0, lA0, 0, 0);
  stage(Bt, nb, lB0, 1, 0); stage(A, m0, lA0, 1, 0);
  stage(Bt, nb, lB1, 0, 1); stage(A, m0, lA1, 0, 1);
  VM4();
  BAR();

#pragma unroll 1
  for (int i = 0; i < 16; ++i) {
    const int o1 = 2 * i + 1, e2 = 2 * i + 2, o3 = 2 * i + 3;
    // p0
    rdA(lA0, 0); rdB(lB0, 0);
    stage(Bt, nb, lB1, 1, o1);
    BAR(); LGK0(); mm(0, 0); BAR();
    // p1
    rdB(lB0, 1);
    stage(A, m0, lA1, 1, o1);
    BAR(); LGK0(); mm(0, 1); BAR();
    // p2
    rdA(lA0, 1);
    stage(Bt, nb, lB0, 0, e2);
    BAR(); LGK0(); mm(1, 0); BAR();
    // p3
    stage(A, m0, lA0, 0, e2);
    BAR(); LGK0(); mm(1, 1);
    VM4(); BAR();
    // p4
    rdA(lA1, 0); rdB(lB1, 0);
    stage(Bt, nb, lB0, 1, e2);
    BAR(); LGK0(); mm(0, 0); BAR();
    // p5
    rdB(lB1, 1);
    stage(A, m0, lA0, 1, e2);
    BAR(); LGK0(); mm(0, 1); BAR();
    // p6
    rdA(lA1, 1);
    stage(Bt, nb, lB1, 0, o3);
    BAR(); LGK0(); mm(1, 0); BAR();
    // p7
    stage(A, m0, lA1, 0, o3);
    BAR(); LGK0(); mm(1, 1);
    VM4(); BAR();
  }
  asm volatile("s_waitcnt vmcnt(0) lgkmcnt(0)" ::: "memory");
}

struct QKV8P {
  const u16* wt[6];      // [type*2 + stream]: q1,q2,k1,k2,v1,v2
  const float* bias[6];
  u16* outq;             // Q bf16 [B,S,D] (rope'd, scaled)
  u16* outk;             // K bf16 [B,S,D] (rope'd)
  u16* vt;               // V bf16 [B,D,S] (transposed)
  const u16* xc;
  const float* tc;       // cosT [128][2048]
  const float* ts;       // sinT [128][2048]
};

// fused QKV + RoPE/V-transpose epilogue: M=4096, N=6144, grid 384
__global__ __launch_bounds__(512, 2) void k_gemm_qkv(QKV8P p) {
  __shared__ __align__(16) u16 lA[2 * 256 * 64];
  __shared__ __align__(16) u16 lB[2 * 256 * 64];
  const int id = blockIdx.x;
  const int xcd = id & 7, sub = id >> 3;
  const int nt = xcd * 3 + (sub >> 4);
  const int mt = sub & 15;
  const int m0 = mt * 256;
  const int type = nt >> 3;                     // 0=q,1=k,2=v
  const int colw = (nt & 7) * 256;
  const int strm = (mt >> 2) & 1;
  const int widx = type * 2 + strm;
  f32x4 acc[8][4];
  const f32x4 z4 = {0.f, 0.f, 0.f, 0.f};
#pragma unroll
  for (int a = 0; a < 8; ++a)
#pragma unroll
    for (int b = 0; b < 4; ++b) acc[a][b] = z4;
  gemm256_core(p.xc, p.wt[widx], m0, colw, lA, lB, acc);
  const int lane = threadIdx.x & 63, wid = threadIdx.x >> 6;
  const int lq = lane & 15, lg = lane >> 4;
  const int wr = wid >> 2, wc = wid & 3;
  const float* bias = p.bias[widx];

  if (type < 2) {
    // Q/K: fused RoPE (+1/sqrt(128) scale for Q)
    u16* out = (type == 0) ? p.outq : p.outk;
    const float scale = (type == 0) ? 0.08838834764831843f : 1.f;
#pragma unroll
    for (int nf = 0; nf < 4; ++nf) {
      int col = colw + wc * 64 + nf * 16 + lq;
      float bv = bias[col];
      int dh = col & 127;
      float sgn = (col & 1) ? 1.f : -1.f;
      const float* cr = p.tc + dh * 2048;
      const float* sr = p.ts + dh * 2048;
#pragma unroll
      for (int mf = 0; mf < 8; ++mf) {
        int row0 = m0 + wr * 128 + mf * 16 + lg * 4;
        int n0 = row0 & 2047;
        float4 cv = *(const float4*)(cr + n0);
        float4 sv = *(const float4*)(sr + n0);
#pragma unroll
        for (int j = 0; j < 4; ++j) {
          float v = acc[mf][nf][j] + bv;
          float pv = __shfl_xor(v, 1);     // partner feature (bias included)
          float cj = (j == 0) ? cv.x : (j == 1) ? cv.y : (j == 2) ? cv.z : cv.w;
          float sj = (j == 0) ? sv.x : (j == 1) ? sv.y : (j == 2) ? sv.z : sv.w;
          float o = (v * cj + sgn * pv * sj) * scale;
          out[(size_t)(row0 + j) * 2048 + col] = f2bf(o);
        }
      }
    }
  } else {
    // V: transpose via LDS (reuse lA, 64 KB, dead after K-loop) then coalesced
    // 16B stores to Vt [B,D,S]. XOR swizzle (rd&7)<<4 applied on BOTH sides.
    const int bb = m0 >> 11, nbase = m0 & 2047;
    float bvv[4];
#pragma unroll
    for (int nf = 0; nf < 4; ++nf) bvv[nf] = bias[colw + wc * 64 + nf * 16 + lq];
    __syncthreads();   // drain all waves' trailing stages before lA reuse
#pragma unroll
    for (int pss = 0; pss < 2; ++pss) {
      if ((wc >> 1) == pss) {
#pragma unroll
        for (int nf = 0; nf < 4; ++nf) {
          int rd = (wc & 1) * 64 + nf * 16 + lq;      // d_local within 128-half
          int swzv = (rd & 7) << 4;
#pragma unroll
          for (int mf = 0; mf < 8; ++mf) {
            int nl0 = wr * 128 + mf * 16 + lg * 4;    // n_local (multiple of 4)
            us4 o = {f2bf(acc[mf][nf][0] + bvv[nf]), f2bf(acc[mf][nf][1] + bvv[nf]),
                     f2bf(acc[mf][nf][2] + bvv[nf]), f2bf(acc[mf][nf][3] + bvv[nf])};
            *(us4*)((char*)lA + rd * 512 + ((nl0 * 2) ^ swzv)) = o;
          }
        }
      }
      __syncthreads();
      // cooperative store: [128 d][256 n] half-tile, 16B per thread-iter
#pragma unroll
      for (int i = 0; i < 8; ++i) {
        int chunk = i * 512 + threadIdx.x;            // 4096 chunks x 16B = 64 KB
        int rd = chunk >> 5;
        int n0l = (chunk & 31) * 8;
        short8 v = *(const short8*)((const char*)lA + rd * 512 +
                                    ((n0l * 2) ^ ((rd & 7) << 4)));
        *(short8*)&p.vt[((size_t)bb * 2048 + colw + pss * 128 + rd) * 2048 +
                        nbase + n0l] = v;
      }
      __syncthreads();
    }
  }
}

// ---------------- m97-style 128x128 GEMM core (out-proj, round-2 proven) ----------------
__device__ __forceinline__ void gemm128_core(const u16* __restrict__ A,
                                             const u16* __restrict__ Bt,
                                             u16* lA, u16* lB,
                                             f32x4 acc[4][4], int m0, int n0) {
  const int t = threadIdx.x;
  const int lane = t & 63;
  const int lq = lane & 15, lg = lane >> 4;
  const int wr = (t >> 7) & 1, wc = (t >> 6) & 1;
  for (int k0 = 0; k0 < 2048; k0 += 64) {
    __syncthreads();
#pragma unroll
    for (int i = 0; i < 4; ++i) {
      int chunk = i * 256 + t;
      int r = chunk >> 3, c = chunk & 7;
      GLL16(A + ((m0 + r) * 2048 + k0 + c * 8), lA + chunk * 8);
      GLL16(Bt + ((n0 + r) * 2048 + k0 + c * 8), lB + chunk * 8);
    }
    asm volatile("s_waitcnt vmcnt(0)" ::: "memory");
    __syncthreads();
#pragma unroll
    for (int kc = 0; kc < 2; ++kc) {
      short8 af[4], bf[4];
#pragma unroll
      for (int rf = 0; rf < 4; ++rf)
        af[rf] = *(const short8*)(lA + (wr * 64 + rf * 16 + lq) * 64 + kc * 32 + lg * 8);
#pragma unroll
      for (int cf = 0; cf < 4; ++cf)
        bf[cf] = *(const short8*)(lB + (wc * 64 + cf * 16 + lq) * 64 + kc * 32 + lg * 8);
#pragma unroll
      for (int rf = 0; rf < 4; ++rf)
#pragma unroll
        for (int cf = 0; cf < 4; ++cf)
          acc[rf][cf] = MFMA16x32(af[rf], bf[cf], acc[rf][cf]);
    }
  }
}

__global__ __launch_bounds__(256) void k_gemm_out(const u16* __restrict__ O,
                                                  const u16* __restrict__ wt0,
                                                  const u16* __restrict__ wt1,
                                                  const float* __restrict__ b0,
                                                  const float* __restrict__ b1,
                                                  float* __restrict__ out) {
  __shared__ u16 lA[128 * 64];
  __shared__ u16 lB[128 * 64];
  const int m0 = blockIdx.x * 128, n0 = blockIdx.y * 128;
  const int stream1 = (m0 >> 10) & 1;
  f32x4 acc[4][4];
  const f32x4 z4 = {0.f, 0.f, 0.f, 0.f};
#pragma unroll
  for (int a = 0; a < 4; ++a)
#pragma unroll
    for (int b = 0; b < 4; ++b) acc[a][b] = z4;
  gemm128_core(O, stream1 ? wt1 : wt0, lA, lB, acc, m0, n0);
  const float* bias = stream1 ? b1 : b0;
  const int lane = threadIdx.x & 63, lq = lane & 15, lg = lane >> 4;
  const int wr = (threadIdx.x >> 7) & 1, wc = (threadIdx.x >> 6) & 1;
#pragma unroll
  for (int cf = 0; cf < 4; ++cf) {
    int col = n0 + wc * 64 + cf * 16 + lq;
    float bv = bias[col];
#pragma unroll
    for (int rf = 0; rf < 4; ++rf) {
      int row0 = m0 + wr * 64 + rf * 16 + lg * 4;
#pragma unroll
      for (int j = 0; j < 4; ++j) {
        int row = row0 + j;
        int b = row >> 11, n = row & 2047;
        float* dst = stream1 ? out + 4194304 + (((b << 10) + n - 1024) * 2048 + col)
                             : out + (((b << 10) + n) * 2048 + col);
        *dst = acc[rf][cf][j] + bv;
      }
    }
  }
}

// ---------------- flash attention (round-9 exact: K+V LDS-staged, no defer-max) ----------------
__global__ __launch_bounds__(256) void k_attn(const u16* __restrict__ Q,
                                              const u16* __restrict__ K,
                                              const u16* __restrict__ Vt,
                                              u16* __restrict__ O) {
  __shared__ __align__(16) u16 kbuf[2][64 * 128];
  __shared__ __align__(16) u16 vbuf[2][128 * 64];
  __shared__ __align__(16) u16 pbuf[4][16 * 88];
  const int t = threadIdx.x, lane = t & 63, w = t >> 6;
  const int lq = lane & 15, g = lane >> 4;
  const int id = blockIdx.x;
  const int lgid = (id & 7) * 64 + (id >> 3);
  const int bh = lgid >> 4, qt = lgid & 15;
  const int b = bh >> 4, h = bh & 15;

  short8 qf[2][4];
#pragma unroll
  for (int u = 0; u < 2; ++u) {
    const u16* Qp = Q + (size_t)(b * 2048 + qt * 128 + w * 32 + u * 16 + lq) * 2048
                    + h * 128 + g * 8;
#pragma unroll
    for (int c = 0; c < 4; ++c) qf[u][c] = *(const short8*)(Qp + c * 32);
  }

  f32x4 oacc[2][8];
  const f32x4 z4 = {0.f, 0.f, 0.f, 0.f};
#pragma unroll
  for (int u = 0; u < 2; ++u)
#pragma unroll
    for (int dc = 0; dc < 8; ++dc) oacc[u][dc] = z4;
  float m_run[2] = {-1e30f, -1e30f}, l_run[2] = {0.f, 0.f};

  const int swz = (lq & 7) << 4;

  auto STAGE = [&](int bs, int kt) {
#pragma unroll
    for (int ii = 0; ii < 4; ++ii) {
      int i = w * 4 + ii;
      int o = i * 1024 + lane * 16;
      {
        int row = o >> 8, colb = o & 255;
        int sc = colb ^ ((row & 7) << 4);
        GLL16(K + (size_t)(b * 2048 + kt + row) * 2048 + h * 128 + (sc >> 1),
              (u16*)((char*)kbuf[bs] + o));
      }
      {
        int row = o >> 7, colb = o & 127;
        int sc = colb ^ ((row & 7) << 4);
        GLL16(Vt + (size_t)(b * 2048 + h * 128 + row) * 2048 + kt + (sc >> 1),
              (u16*)((char*)vbuf[bs] + o));
      }
    }
  };

  STAGE(0, 0);
  asm volatile("s_waitcnt vmcnt(0)" ::: "memory");
  __syncthreads();

  for (int tt = 0; tt < 32; ++tt) {
    const int cb = tt & 1;
    if (tt < 31) STAGE(cb ^ 1, (tt + 1) * 64);

    const char* kb = (const char*)kbuf[cb];
    const char* vb = (const char*)vbuf[cb];
    f32x4 s[2][4];
#pragma unroll
    for (int u = 0; u < 2; ++u)
#pragma unroll
      for (int kg = 0; kg < 4; ++kg) s[u][kg] = z4;
#pragma unroll
    for (int c = 0; c < 4; ++c) {
#pragma unroll
      for (int kg = 0; kg < 4; ++kg) {
        short8 kf = *(const short8*)(kb + (kg * 16 + lq) * 256 + ((c * 64 + g * 16) ^ swz));
        s[0][kg] = MFMA16x32(kf, qf[0][c], s[0][kg]);
        s[1][kg] = MFMA16x32(kf, qf[1][c], s[1][kg]);
      }
    }
    u16* pw = pbuf[w];
    short8 pb[2][2];
#pragma unroll
    for (int u = 0; u < 2; ++u) {
      float pm = -1e30f;
#pragma unroll
      for (int kg = 0; kg < 4; ++kg)
#pragma unroll
        for (int j = 0; j < 4; ++j) pm = fmaxf(pm, s[u][kg][j]);
      pm = fmaxf(pm, __shfl_xor(pm, 16));
      pm = fmaxf(pm, __shfl_xor(pm, 32));
      const float mnew = fmaxf(m_run[u], pm);
      const float r = __expf(m_run[u] - mnew);
      m_run[u] = mnew;
      float ps = 0.f;
#pragma unroll
      for (int kg = 0; kg < 4; ++kg) {
        float p0 = __expf(s[u][kg][0] - mnew), p1 = __expf(s[u][kg][1] - mnew);
        float p2 = __expf(s[u][kg][2] - mnew), p3 = __expf(s[u][kg][3] - mnew);
        ps += (p0 + p1) + (p2 + p3);
        us4 wv = {f2bf(p0), f2bf(p1), f2bf(p2), f2bf(p3)};
        *(us4*)(pw + lq * 88 + kg * 16 + g * 4) = wv;
      }
      ps += __shfl_xor(ps, 16);
      ps += __shfl_xor(ps, 32);
      l_run[u] = l_run[u] * r + ps;
#pragma unroll
      for (int dc = 0; dc < 8; ++dc) oacc[u][dc] = oacc[u][dc] * r;
      pb[u][0] = *(const short8*)(pw + lq * 88 + g * 8);
      pb[u][1] = *(const short8*)(pw + lq * 88 + 32 + g * 8);
    }
#pragma unroll
    for (int kc = 0; kc < 2; ++kc) {
#pragma unroll
      for (int dc = 0; dc < 8; ++dc) {
        short8 vf = *(const short8*)(vb + (dc * 16 + lq) * 128 + ((kc * 64 + g * 16) ^ swz));
        oacc[0][dc] = MFMA16x32(vf, pb[0][kc], oacc[0][dc]);
        oacc[1][dc] = MFMA16x32(vf, pb[1][kc], oacc[1][dc]);
      }
    }
    asm volatile("s_waitcnt vmcnt(0)" ::: "memory");
    __syncthreads();
  }

#pragma unroll
  for (int u = 0; u < 2; ++u) {
    const float inv = 1.f / l_run[u];
    u16* Op = O + (size_t)(b * 2048 + qt * 128 + w * 32 + u * 16 + lq) * 2048
              + h * 128 + g * 4;
#pragma unroll
    for (int dc = 0; dc < 8; ++dc) {
      us4 ov = {f2bf(oacc[u][dc][0] * inv), f2bf(oacc[u][dc][1] * inv),
                f2bf(oacc[u][dc][2] * inv), f2bf(oacc[u][dc][3] * inv)};
      *(us4*)(Op + dc * 16) = ov;
    }
  }
}

// ---------------- host ----------------

extern "C" void kernel_launch(void* const* d_in, const int* in_sizes, int n_in,
                              void* d_out, int out_size, void* d_ws, size_t ws_size,
                              hipStream_t stream) {
  const float* x1   = (const float*)d_in[0];
  const float* x2   = (const float*)d_in[1];
  const float* cos1 = (const float*)d_in[2];
  const float* sin1 = (const float*)d_in[3];
  const float* cos2 = (const float*)d_in[4];
  const float* sin2 = (const float*)d_in[5];
  W8 wp; const float* bias[8];
  for (int i = 0; i < 8; ++i) {
    wp.w[i] = (const float*)d_in[6 + 2 * i];
    bias[i] = (const float*)d_in[7 + 2 * i];
  }
  float* out = (float*)d_out;
  u16* ws = (u16*)d_ws;
  const size_t NX = 8388608;    // B*S*D
  const size_t WSZ = 4194304;   // 2048*2048
  u16* xc = ws;
  u16* wt = ws + NX;
  u16* Qb = wt + 8 * WSZ;
  u16* Kb = Qb + NX;
  u16* Vt = Kb + NX;
  u16* Ob = Vt + NX;
  if (ws_size < (size_t)((Ob + NX) - ws) * sizeof(u16)) return;
  // rope tables (f32, 2 MB) live in the Ob region until attn overwrites it
  float* tabc = (float*)Ob;
  float* tabs = tabc + 262144;

  k_convert_x<<<dim3(4096), dim3(256), 0, stream>>>(x1, x2, xc);
  k_wt<<<dim3(32, 32, 8), dim3(256), 0, stream>>>(wp, wt);
  k_tab<<<dim3(16, 2, 4), dim3(256), 0, stream>>>(cos1, sin1, cos2, sin2, tabc, tabs);

  QKV8P qp;
  qp.wt[0] = wt + 0 * WSZ; qp.wt[1] = wt + 4 * WSZ;   // wq1, wq2
  qp.wt[2] = wt + 1 * WSZ; qp.wt[3] = wt + 5 * WSZ;   // wk1, wk2
  qp.wt[4] = wt + 2 * WSZ; qp.wt[5] = wt + 6 * WSZ;   // wv1, wv2
  qp.bias[0] = bias[0]; qp.bias[1] = bias[4];
  qp.bias[2] = bias[1]; qp.bias[3] = bias[5];
  qp.bias[4] = bias[2]; qp.bias[5] = bias[6];
  qp.outq = Qb; qp.outk = Kb; qp.vt = Vt;
  qp.xc = xc;
  qp.tc = tabc; qp.ts = tabs;
  k_gemm_qkv<<<dim3(384), dim3(512), 0, stream>>>(qp);

  k_attn<<<dim3(512), dim3(256), 0, stream>>>(Qb, Kb, Vt, Ob);
  k_gemm_out<<<dim3(32, 16), dim3(256), 0, stream>>>(Ob, wt + 3 * WSZ, wt + 7 * WSZ,
                                                     bias[3], bias[7], out);
}

// Round 15
// 339.565 us; speedup vs baseline: 1.0368x; 1.0368x over previous
//
#include <hip/hip_runtime.h>
#include <hip/hip_bf16.h>

typedef __attribute__((ext_vector_type(4))) float f32x4;
typedef __attribute__((ext_vector_type(8))) short short8;
typedef __attribute__((ext_vector_type(4))) unsigned short us4;
typedef __attribute__((ext_vector_type(2))) unsigned short us2;
typedef unsigned short u16;

__device__ __forceinline__ float bf2f(u16 u) {
  unsigned int x = ((unsigned int)u) << 16;
  float f; __builtin_memcpy(&f, &x, 4); return f;
}
__device__ __forceinline__ u16 f2bf(float f) {
  __hip_bfloat16 h = __float2bfloat16(f);
  u16 u; __builtin_memcpy(&u, &h, 2); return u;
}

// async global->LDS, 16B per lane. LDS dest must be (wave-uniform base + lane*16).
#define GLL16(g, l) __builtin_amdgcn_global_load_lds( \
    (const __attribute__((address_space(1))) unsigned int*)(g), \
    (__attribute__((address_space(3))) unsigned int*)(l), 16, 0, 0)

#define MFMA16x32(a, b, c) __builtin_amdgcn_mfma_f32_16x16x32_bf16(a, b, c, 0, 0, 0)

// ---------------- conversion kernels ----------------

__global__ __launch_bounds__(256) void k_convert_x(const float* __restrict__ x1,
                                                   const float* __restrict__ x2,
                                                   u16* __restrict__ xc) {
  int tid = blockIdx.x * 256 + threadIdx.x;
  int e = tid * 8;
  int m = e >> 11, d = e & 2047;
  int b = m >> 11, n = m & 2047;
  const float* src = (n < 1024) ? (x1 + ((b << 10) + n) * 2048 + d)
                                : (x2 + ((b << 10) + n - 1024) * 2048 + d);
  float4 v0 = *(const float4*)src;
  float4 v1 = *(const float4*)(src + 4);
  us4 a = {f2bf(v0.x), f2bf(v0.y), f2bf(v0.z), f2bf(v0.w)};
  us4 c = {f2bf(v1.x), f2bf(v1.y), f2bf(v1.z), f2bf(v1.w)};
  *(us4*)(xc + e) = a;
  *(us4*)(xc + e + 4) = c;
}

struct W8 { const float* w[8]; };

// W f32 [K=2048][N=2048] -> Wt bf16 [N][K]
__global__ __launch_bounds__(256) void k_wt(W8 p, u16* __restrict__ wtbase) {
  __shared__ u16 lt[64][72];
  const float* W = p.w[blockIdx.z];
  u16* Wt = wtbase + (size_t)blockIdx.z * 4194304u;
  int k0 = blockIdx.x * 64, n0 = blockIdx.y * 64;
  int t = threadIdx.x;
#pragma unroll
  for (int i = 0; i < 4; ++i) {
    int lin = t + i * 256;
    int r = lin >> 4, c4 = (lin & 15) * 4;
    float4 v = *(const float4*)&W[(k0 + r) * 2048 + n0 + c4];
    us4 u = {f2bf(v.x), f2bf(v.y), f2bf(v.z), f2bf(v.w)};
    *(us4*)&lt[r][c4] = u;
  }
  __syncthreads();
#pragma unroll
  for (int i = 0; i < 8; ++i) {
    int lin = t + i * 256;
    int rd = lin >> 5, cs = (lin & 31) * 2;
    us2 u = {lt[cs][rd], lt[cs + 1][rd]};
    *(us2*)&Wt[(n0 + rd) * 2048 + k0 + cs] = u;
  }
}

// rope tables [1024][128] f32 -> transposed [128][2048] f32 (cols base..base+1023)
__global__ __launch_bounds__(256) void k_tab(const float* __restrict__ c1,
                                             const float* __restrict__ s1,
                                             const float* __restrict__ c2,
                                             const float* __restrict__ s2,
                                             float* __restrict__ tc,
                                             float* __restrict__ ts) {
  __shared__ float lt[64][65];
  const int z = blockIdx.z;                  // 0:c1 1:c2 2:s1 3:s2
  const float* src = (z == 0) ? c1 : (z == 1) ? c2 : (z == 2) ? s1 : s2;
  float* dst = (z < 2) ? tc : ts;
  const int nbase = (z & 1) * 1024;
  const int r0 = blockIdx.x * 64;            // n rows (0..1023)
  const int c0 = blockIdx.y * 64;            // dh cols (0..127)
  const int t = threadIdx.x;
#pragma unroll
  for (int i = 0; i < 4; ++i) {
    int lin = t + i * 256;
    int r = lin >> 4, c4 = (lin & 15) * 4;
    float4 v = *(const float4*)&src[(r0 + r) * 128 + c0 + c4];
    lt[r][c4] = v.x; lt[r][c4 + 1] = v.y; lt[r][c4 + 2] = v.z; lt[r][c4 + 3] = v.w;
  }
  __syncthreads();
#pragma unroll
  for (int i = 0; i < 4; ++i) {
    int lin = t + i * 256;
    int rd = lin >> 4, cs = (lin & 15) * 4;
    float4 w = {lt[cs][rd], lt[cs + 1][rd], lt[cs + 2][rd], lt[cs + 3][rd]};
    *(float4*)&dst[(c0 + rd) * 2048 + nbase + r0 + cs] = w;
  }
}

// ---------------- 8-phase GEMM core ----------------
#define BAR() __builtin_amdgcn_s_barrier()
#define VM4() asm volatile("s_waitcnt vmcnt(4)" ::: "memory")
#define LGK0() do { asm volatile("s_waitcnt lgkmcnt(0)" ::: "memory"); \
                    __builtin_amdgcn_sched_barrier(0); } while (0)

__device__ __forceinline__ void gemm256_core(const u16* __restrict__ A,
                                             const u16* __restrict__ Bt,
                                             int m0, int nb,
                                             u16* lA, u16* lB,
                                             f32x4 acc[8][4]) {
  const int t = threadIdx.x;
  const int lane = t & 63, wid = t >> 6;
  const int lq = lane & 15, lg = lane >> 4;
  const int wr = wid >> 2, wc = wid & 3;
  const int swz = (lq & 7) << 4;

  u16* lA0 = lA;  u16* lA1 = lA + 256 * 64;
  u16* lB0 = lB;  u16* lB1 = lB + 256 * 64;

  short8 af[4][2];
  short8 bf[2][2][2];

  auto stage = [&](const u16* G, int grow0, u16* lbase, int h, int kt) {
    const int k0 = (kt & 31) * 64;
#pragma unroll
    for (int j = 0; j < 2; ++j) {
      int c = j * 512 + t;
      int row = c >> 3;
      int colb = (c & 7) * 16;
      int sc = colb ^ ((row & 7) << 4);
      GLL16(G + (size_t)(grow0 + h * 128 + row) * 2048 + k0 + (sc >> 1),
            (u16*)((char*)lbase + (h * 128 + row) * 128 + colb));
    }
  };
  auto rdA = [&](const u16* lbase, int mh) {
#pragma unroll
    for (int mf = 0; mf < 4; ++mf)
#pragma unroll
      for (int kc = 0; kc < 2; ++kc) {
        int row = wr * 128 + (mh * 4 + mf) * 16 + lq;
        af[mf][kc] = *(const short8*)((const char*)lbase + row * 128 +
                                      ((kc * 64 + lg * 16) ^ swz));
      }
  };
  auto rdB = [&](const u16* lbase, int nh) {
#pragma unroll
    for (int nf = 0; nf < 2; ++nf)
#pragma unroll
      for (int kc = 0; kc < 2; ++kc) {
        int row = wc * 64 + (nh * 2 + nf) * 16 + lq;
        bf[nh][nf][kc] = *(const short8*)((const char*)lbase + row * 128 +
                                          ((kc * 64 + lg * 16) ^ swz));
      }
  };
  auto mm = [&](int mh, int nh) {
    __builtin_amdgcn_s_setprio(1);
#pragma unroll
    for (int mf = 0; mf < 4; ++mf)
#pragma unroll
      for (int nf = 0; nf < 2; ++nf)
#pragma unroll
        for (int kc = 0; kc < 2; ++kc)
          acc[mh * 4 + mf][nh * 2 + nf] =
              MFMA16x32(af[mf][kc], bf[nh][nf][kc], acc[mh * 4 + mf][nh * 2 + nf]);
    __builtin_amdgcn_s_setprio(0);
  };

  // prologue: tile0 complete, tile1 {B-h0, A-h0}
  stage(Bt, nb, lB0, 0, 0); stage(A, m0, lA0, 0, 0);
  stage(Bt, nb, lB0, 1, 0); stage(A, m0, lA0, 1, 0);
  stage(Bt, nb, lB1, 0, 1); stage(A, m0, lA1, 0, 1);
  VM4();
  BAR();

#pragma unroll 1
  for (int i = 0; i < 16; ++i) {
    const int o1 = 2 * i + 1, e2 = 2 * i + 2, o3 = 2 * i + 3;
    // p0
    rdA(lA0, 0); rdB(lB0, 0);
    stage(Bt, nb, lB1, 1, o1);
    BAR(); LGK0(); mm(0, 0); BAR();
    // p1
    rdB(lB0, 1);
    stage(A, m0, lA1, 1, o1);
    BAR(); LGK0(); mm(0, 1); BAR();
    // p2
    rdA(lA0, 1);
    stage(Bt, nb, lB0, 0, e2);
    BAR(); LGK0(); mm(1, 0); BAR();
    // p3
    stage(A, m0, lA0, 0, e2);
    BAR(); LGK0(); mm(1, 1);
    VM4(); BAR();
    // p4
    rdA(lA1, 0); rdB(lB1, 0);
    stage(Bt, nb, lB0, 1, e2);
    BAR(); LGK0(); mm(0, 0); BAR();
    // p5
    rdB(lB1, 1);
    stage(A, m0, lA0, 1, e2);
    BAR(); LGK0(); mm(0, 1); BAR();
    // p6
    rdA(lA1, 1);
    stage(Bt, nb, lB1, 0, o3);
    BAR(); LGK0(); mm(1, 0); BAR();
    // p7
    stage(A, m0, lA1, 0, o3);
    BAR(); LGK0(); mm(1, 1);
    VM4(); BAR();
  }
  asm volatile("s_waitcnt vmcnt(0) lgkmcnt(0)" ::: "memory");
}

struct QKV8P {
  const u16* wt[6];      // [type*2 + stream]: q1,q2,k1,k2,v1,v2
  const float* bias[6];
  u16* outq;             // Q bf16 [B,S,D] (rope'd, scaled)
  u16* outk;             // K bf16 [B,S,D] (rope'd)
  u16* vt;               // V bf16 [B,D,S] (transposed)
  const u16* xc;
  const float* tc;       // cosT [128][2048]
  const float* ts;       // sinT [128][2048]
};

// fused QKV + RoPE/V-transpose epilogue: M=4096, N=6144, grid 384
__global__ __launch_bounds__(512, 2) void k_gemm_qkv(QKV8P p) {
  __shared__ __align__(16) u16 lA[2 * 256 * 64];
  __shared__ __align__(16) u16 lB[2 * 256 * 64];
  const int id = blockIdx.x;
  const int xcd = id & 7, sub = id >> 3;
  const int nt = xcd * 3 + (sub >> 4);
  const int mt = sub & 15;
  const int m0 = mt * 256;
  const int type = nt >> 3;                     // 0=q,1=k,2=v
  const int colw = (nt & 7) * 256;
  const int strm = (mt >> 2) & 1;
  const int widx = type * 2 + strm;
  f32x4 acc[8][4];
  const f32x4 z4 = {0.f, 0.f, 0.f, 0.f};
#pragma unroll
  for (int a = 0; a < 8; ++a)
#pragma unroll
    for (int b = 0; b < 4; ++b) acc[a][b] = z4;
  gemm256_core(p.xc, p.wt[widx], m0, colw, lA, lB, acc);
  const int lane = threadIdx.x & 63, wid = threadIdx.x >> 6;
  const int lq = lane & 15, lg = lane >> 4;
  const int wr = wid >> 2, wc = wid & 3;
  const float* bias = p.bias[widx];

  if (type < 2) {
    // Q/K: fused RoPE (+1/sqrt(128) scale for Q)
    u16* out = (type == 0) ? p.outq : p.outk;
    const float scale = (type == 0) ? 0.08838834764831843f : 1.f;
#pragma unroll
    for (int nf = 0; nf < 4; ++nf) {
      int col = colw + wc * 64 + nf * 16 + lq;
      float bv = bias[col];
      int dh = col & 127;
      float sgn = (col & 1) ? 1.f : -1.f;
      const float* cr = p.tc + dh * 2048;
      const float* sr = p.ts + dh * 2048;
#pragma unroll
      for (int mf = 0; mf < 8; ++mf) {
        int row0 = m0 + wr * 128 + mf * 16 + lg * 4;
        int n0 = row0 & 2047;
        float4 cv = *(const float4*)(cr + n0);
        float4 sv = *(const float4*)(sr + n0);
#pragma unroll
        for (int j = 0; j < 4; ++j) {
          float v = acc[mf][nf][j] + bv;
          float pv = __shfl_xor(v, 1);     // partner feature (bias included)
          float cj = (j == 0) ? cv.x : (j == 1) ? cv.y : (j == 2) ? cv.z : cv.w;
          float sj = (j == 0) ? sv.x : (j == 1) ? sv.y : (j == 2) ? sv.z : sv.w;
          float o = (v * cj + sgn * pv * sj) * scale;
          out[(size_t)(row0 + j) * 2048 + col] = f2bf(o);
        }
      }
    }
  } else {
    // V: transpose via LDS (reuse lA, dead after K-loop) then coalesced 16B stores
    const int bb = m0 >> 11, nbase = m0 & 2047;
    float bvv[4];
#pragma unroll
    for (int nf = 0; nf < 4; ++nf) bvv[nf] = bias[colw + wc * 64 + nf * 16 + lq];
    __syncthreads();   // drain all waves' trailing stages before lA reuse
#pragma unroll
    for (int pss = 0; pss < 2; ++pss) {
      if ((wc >> 1) == pss) {
#pragma unroll
        for (int nf = 0; nf < 4; ++nf) {
          int rd = (wc & 1) * 64 + nf * 16 + lq;      // d_local within 128-half
          int swzv = (rd & 7) << 4;
#pragma unroll
          for (int mf = 0; mf < 8; ++mf) {
            int nl0 = wr * 128 + mf * 16 + lg * 4;    // n_local (multiple of 4)
            us4 o = {f2bf(acc[mf][nf][0] + bvv[nf]), f2bf(acc[mf][nf][1] + bvv[nf]),
                     f2bf(acc[mf][nf][2] + bvv[nf]), f2bf(acc[mf][nf][3] + bvv[nf])};
            *(us4*)((char*)lA + rd * 512 + ((nl0 * 2) ^ swzv)) = o;
          }
        }
      }
      __syncthreads();
#pragma unroll
      for (int i = 0; i < 8; ++i) {
        int chunk = i * 512 + threadIdx.x;            // 4096 chunks x 16B = 64 KB
        int rd = chunk >> 5;
        int n0l = (chunk & 31) * 8;
        short8 v = *(const short8*)((const char*)lA + rd * 512 +
                                    ((n0l * 2) ^ ((rd & 7) << 4)));
        *(short8*)&p.vt[((size_t)bb * 2048 + colw + pss * 128 + rd) * 2048 +
                        nbase + n0l] = v;
      }
      __syncthreads();
    }
  }
}

// ---------------- m97-style 128x128 GEMM core (out-proj, round-2 proven) ----------------
__device__ __forceinline__ void gemm128_core(const u16* __restrict__ A,
                                             const u16* __restrict__ Bt,
                                             u16* lA, u16* lB,
                                             f32x4 acc[4][4], int m0, int n0) {
  const int t = threadIdx.x;
  const int lane = t & 63;
  const int lq = lane & 15, lg = lane >> 4;
  const int wr = (t >> 7) & 1, wc = (t >> 6) & 1;
  for (int k0 = 0; k0 < 2048; k0 += 64) {
    __syncthreads();
#pragma unroll
    for (int i = 0; i < 4; ++i) {
      int chunk = i * 256 + t;
      int r = chunk >> 3, c = chunk & 7;
      GLL16(A + ((m0 + r) * 2048 + k0 + c * 8), lA + chunk * 8);
      GLL16(Bt + ((n0 + r) * 2048 + k0 + c * 8), lB + chunk * 8);
    }
    asm volatile("s_waitcnt vmcnt(0)" ::: "memory");
    __syncthreads();
#pragma unroll
    for (int kc = 0; kc < 2; ++kc) {
      short8 af[4], bf[4];
#pragma unroll
      for (int rf = 0; rf < 4; ++rf)
        af[rf] = *(const short8*)(lA + (wr * 64 + rf * 16 + lq) * 64 + kc * 32 + lg * 8);
#pragma unroll
      for (int cf = 0; cf < 4; ++cf)
        bf[cf] = *(const short8*)(lB + (wc * 64 + cf * 16 + lq) * 64 + kc * 32 + lg * 8);
#pragma unroll
      for (int rf = 0; rf < 4; ++rf)
#pragma unroll
        for (int cf = 0; cf < 4; ++cf)
          acc[rf][cf] = MFMA16x32(af[rf], bf[cf], acc[rf][cf]);
    }
  }
}

__global__ __launch_bounds__(256) void k_gemm_out(const u16* __restrict__ O,
                                                  const u16* __restrict__ wt0,
                                                  const u16* __restrict__ wt1,
                                                  const float* __restrict__ b0,
                                                  const float* __restrict__ b1,
                                                  float* __restrict__ out) {
  __shared__ u16 lA[128 * 64];
  __shared__ u16 lB[128 * 64];
  const int m0 = blockIdx.x * 128, n0 = blockIdx.y * 128;
  const int stream1 = (m0 >> 10) & 1;
  f32x4 acc[4][4];
  const f32x4 z4 = {0.f, 0.f, 0.f, 0.f};
#pragma unroll
  for (int a = 0; a < 4; ++a)
#pragma unroll
    for (int b = 0; b < 4; ++b) acc[a][b] = z4;
  gemm128_core(O, stream1 ? wt1 : wt0, lA, lB, acc, m0, n0);
  const float* bias = stream1 ? b1 : b0;
  const int lane = threadIdx.x & 63, lq = lane & 15, lg = lane >> 4;
  const int wr = (threadIdx.x >> 7) & 1, wc = (threadIdx.x >> 6) & 1;
#pragma unroll
  for (int cf = 0; cf < 4; ++cf) {
    int col = n0 + wc * 64 + cf * 16 + lq;
    float bv = bias[col];
#pragma unroll
    for (int rf = 0; rf < 4; ++rf) {
      int row0 = m0 + wr * 64 + rf * 16 + lg * 4;
#pragma unroll
      for (int j = 0; j < 4; ++j) {
        int row = row0 + j;
        int b = row >> 11, n = row & 2047;
        float* dst = stream1 ? out + 4194304 + (((b << 10) + n - 1024) * 2048 + col)
                             : out + (((b << 10) + n) * 2048 + col);
        *dst = acc[rf][cf][j] + bv;
      }
    }
  }
}

// ---------------- flash attention v3: 8 waves, 256 q-rows/block, shared K/V staging ----------------
// Halves per-XCD L2 re-read amplification (16x -> 8x). Grid 256 = exactly 1 round.
__global__ __launch_bounds__(512) void k_attn(const u16* __restrict__ Q,
                                              const u16* __restrict__ K,
                                              const u16* __restrict__ Vt,
                                              u16* __restrict__ O) {
  __shared__ __align__(16) u16 kbuf[2][64 * 128];
  __shared__ __align__(16) u16 vbuf[2][128 * 64];
  __shared__ __align__(16) u16 pbuf[8][16 * 88];
  const int t = threadIdx.x, lane = t & 63, w = t >> 6;      // w in [0,8)
  const int lq = lane & 15, g = lane >> 4;
  const int id = blockIdx.x;                                  // 256 blocks
  const int lgid = (id & 7) * 32 + (id >> 3);                 // XCD-chunked
  const int bh = lgid >> 3, qt = lgid & 7;                    // 8 q-tiles of 256
  const int b = bh >> 4, h = bh & 15;

  short8 qf[2][4];
#pragma unroll
  for (int u = 0; u < 2; ++u) {
    const u16* Qp = Q + (size_t)(b * 2048 + qt * 256 + w * 32 + u * 16 + lq) * 2048
                    + h * 128 + g * 8;
#pragma unroll
    for (int c = 0; c < 4; ++c) qf[u][c] = *(const short8*)(Qp + c * 32);
  }

  f32x4 oacc[2][8];
  const f32x4 z4 = {0.f, 0.f, 0.f, 0.f};
#pragma unroll
  for (int u = 0; u < 2; ++u)
#pragma unroll
    for (int dc = 0; dc < 8; ++dc) oacc[u][dc] = z4;
  float m_run[2] = {-1e30f, -1e30f}, l_run[2] = {0.f, 0.f};

  const int swz = (lq & 7) << 4;

  auto STAGE = [&](int bs, int kt) {
#pragma unroll
    for (int ii = 0; ii < 2; ++ii) {
      int i = w * 2 + ii;                    // 16 chunks over 8 waves
      int o = i * 1024 + lane * 16;
      {
        int row = o >> 8, colb = o & 255;
        int sc = colb ^ ((row & 7) << 4);
        GLL16(K + (size_t)(b * 2048 + kt + row) * 2048 + h * 128 + (sc >> 1),
              (u16*)((char*)kbuf[bs] + o));
      }
      {
        int row = o >> 7, colb = o & 127;
        int sc = colb ^ ((row & 7) << 4);
        GLL16(Vt + (size_t)(b * 2048 + h * 128 + row) * 2048 + kt + (sc >> 1),
              (u16*)((char*)vbuf[bs] + o));
      }
    }
  };

  STAGE(0, 0);
  asm volatile("s_waitcnt vmcnt(0)" ::: "memory");
  __syncthreads();

  for (int tt = 0; tt < 32; ++tt) {
    const int cb = tt & 1;
    if (tt < 31) STAGE(cb ^ 1, (tt + 1) * 64);

    const char* kb = (const char*)kbuf[cb];
    const char* vb = (const char*)vbuf[cb];
    f32x4 s[2][4];
#pragma unroll
    for (int u = 0; u < 2; ++u)
#pragma unroll
      for (int kg = 0; kg < 4; ++kg) s[u][kg] = z4;
#pragma unroll
    for (int c = 0; c < 4; ++c) {
#pragma unroll
      for (int kg = 0; kg < 4; ++kg) {
        short8 kf = *(const short8*)(kb + (kg * 16 + lq) * 256 + ((c * 64 + g * 16) ^ swz));
        s[0][kg] = MFMA16x32(kf, qf[0][c], s[0][kg]);
        s[1][kg] = MFMA16x32(kf, qf[1][c], s[1][kg]);
      }
    }
    u16* pw = pbuf[w];
    short8 pb[2][2];
#pragma unroll
    for (int u = 0; u < 2; ++u) {
      float pm = -1e30f;
#pragma unroll
      for (int kg = 0; kg < 4; ++kg)
#pragma unroll
        for (int j = 0; j < 4; ++j) pm = fmaxf(pm, s[u][kg][j]);
      pm = fmaxf(pm, __shfl_xor(pm, 16));
      pm = fmaxf(pm, __shfl_xor(pm, 32));
      const float mnew = fmaxf(m_run[u], pm);
      const float r = __expf(m_run[u] - mnew);
      m_run[u] = mnew;
      float ps = 0.f;
#pragma unroll
      for (int kg = 0; kg < 4; ++kg) {
        float p0 = __expf(s[u][kg][0] - mnew), p1 = __expf(s[u][kg][1] - mnew);
        float p2 = __expf(s[u][kg][2] - mnew), p3 = __expf(s[u][kg][3] - mnew);
        ps += (p0 + p1) + (p2 + p3);
        us4 wv = {f2bf(p0), f2bf(p1), f2bf(p2), f2bf(p3)};
        *(us4*)(pw + lq * 88 + kg * 16 + g * 4) = wv;
      }
      ps += __shfl_xor(ps, 16);
      ps += __shfl_xor(ps, 32);
      l_run[u] = l_run[u] * r + ps;
#pragma unroll
      for (int dc = 0; dc < 8; ++dc) oacc[u][dc] = oacc[u][dc] * r;
      pb[u][0] = *(const short8*)(pw + lq * 88 + g * 8);
      pb[u][1] = *(const short8*)(pw + lq * 88 + 32 + g * 8);
    }
#pragma unroll
    for (int kc = 0; kc < 2; ++kc) {
#pragma unroll
      for (int dc = 0; dc < 8; ++dc) {
        short8 vf = *(const short8*)(vb + (dc * 16 + lq) * 128 + ((kc * 64 + g * 16) ^ swz));
        oacc[0][dc] = MFMA16x32(vf, pb[0][kc], oacc[0][dc]);
        oacc[1][dc] = MFMA16x32(vf, pb[1][kc], oacc[1][dc]);
      }
    }
    asm volatile("s_waitcnt vmcnt(0)" ::: "memory");
    __syncthreads();
  }

#pragma unroll
  for (int u = 0; u < 2; ++u) {
    const float inv = 1.f / l_run[u];
    u16* Op = O + (size_t)(b * 2048 + qt * 256 + w * 32 + u * 16 + lq) * 2048
              + h * 128 + g * 4;
#pragma unroll
    for (int dc = 0; dc < 8; ++dc) {
      us4 ov = {f2bf(oacc[u][dc][0] * inv), f2bf(oacc[u][dc][1] * inv),
                f2bf(oacc[u][dc][2] * inv), f2bf(oacc[u][dc][3] * inv)};
      *(us4*)(Op + dc * 16) = ov;
    }
  }
}

// ---------------- host ----------------

extern "C" void kernel_launch(void* const* d_in, const int* in_sizes, int n_in,
                              void* d_out, int out_size, void* d_ws, size_t ws_size,
                              hipStream_t stream) {
  const float* x1   = (const float*)d_in[0];
  const float* x2   = (const float*)d_in[1];
  const float* cos1 = (const float*)d_in[2];
  const float* sin1 = (const float*)d_in[3];
  const float* cos2 = (const float*)d_in[4];
  const float* sin2 = (const float*)d_in[5];
  W8 wp; const float* bias[8];
  for (int i = 0; i < 8; ++i) {
    wp.w[i] = (const float*)d_in[6 + 2 * i];
    bias[i] = (const float*)d_in[7 + 2 * i];
  }
  float* out = (float*)d_out;
  u16* ws = (u16*)d_ws;
  const size_t NX = 8388608;    // B*S*D
  const size_t WSZ = 4194304;   // 2048*2048
  u16* xc = ws;
  u16* wt = ws + NX;
  u16* Qb = wt + 8 * WSZ;
  u16* Kb = Qb + NX;
  u16* Vt = Kb + NX;
  u16* Ob = Vt + NX;
  if (ws_size < (size_t)((Ob + NX) - ws) * sizeof(u16)) return;
  // rope tables (f32, 2 MB) live in the Ob region until attn overwrites it
  float* tabc = (float*)Ob;
  float* tabs = tabc + 262144;

  k_convert_x<<<dim3(4096), dim3(256), 0, stream>>>(x1, x2, xc);
  k_wt<<<dim3(32, 32, 8), dim3(256), 0, stream>>>(wp, wt);
  k_tab<<<dim3(16, 2, 4), dim3(256), 0, stream>>>(cos1, sin1, cos2, sin2, tabc, tabs);

  QKV8P qp;
  qp.wt[0] = wt + 0 * WSZ; qp.wt[1] = wt + 4 * WSZ;   // wq1, wq2
  qp.wt[2] = wt + 1 * WSZ; qp.wt[3] = wt + 5 * WSZ;   // wk1, wk2
  qp.wt[4] = wt + 2 * WSZ; qp.wt[5] = wt + 6 * WSZ;   // wv1, wv2
  qp.bias[0] = bias[0]; qp.bias[1] = bias[4];
  qp.bias[2] = bias[1]; qp.bias[3] = bias[5];
  qp.bias[4] = bias[2]; qp.bias[5] = bias[6];
  qp.outq = Qb; qp.outk = Kb; qp.vt = Vt;
  qp.xc = xc;
  qp.tc = tabc; qp.ts = tabs;
  k_gemm_qkv<<<dim3(384), dim3(512), 0, stream>>>(qp);

  k_attn<<<dim3(256), dim3(512), 0, stream>>>(Qb, Kb, Vt, Ob);
  k_gemm_out<<<dim3(32, 16), dim3(256), 0, stream>>>(Ob, wt + 3 * WSZ, wt + 7 * WSZ,
                                                     bias[3], bias[7], out);
}